// Round 3
// baseline (399.545 us; speedup 1.0000x reference)
//
#include <hip/hip_runtime.h>

// RecursiveEncoder on MI355X. B=16, H=256, S=16, C=5, L=6, N_LEAF=15625, N_INT=3906.
// R8: kill the A-gather stall (R7: conflicts=0 but 55% of level_kernel = vmcnt
//     stall on 64B gathered slices over 128MB). Child features are now written
//     DIRECTLY in bucket-gather order (writers already scatter, so permuting the
//     destination is free): G_l[slot] = concat child feats for parent at bucket
//     slot. dest_kernel fills per-node write slots (wdest) after bucket_kernel.
//     level_kernel A-read becomes a contiguous 320KB/block stream -> depth-2
//     counted-vmcnt pipeline actually covers latency. Pipeline/swizzle from R7.

#define B_ 16
#define H_ 256
#define NLEAF 15625
#define NINT 3906

typedef __bf16 bf16_t;
typedef bf16_t bf16x8 __attribute__((ext_vector_type(8)));
typedef bf16_t bf16x4 __attribute__((ext_vector_type(4)));
typedef float f32x4 __attribute__((ext_vector_type(4)));

__device__ __forceinline__ void gl2lds16(const bf16_t* g, bf16_t* l) {
  __builtin_amdgcn_global_load_lds((const __attribute__((address_space(1))) void*)g,
                                   (__attribute__((address_space(3))) void*)l,
                                   16, 0, 0);
}

// grid(240): t(3) x kc(80), 16 k each. Reads coalesced across lanes, 16B stores.
__global__ __launch_bounds__(256) void prep_kernel(const float* __restrict__ W_node,
                                                   bf16_t* __restrict__ Wt,
                                                   int* __restrict__ counters) {
  if (blockIdx.x == 0 && threadIdx.x < 18) counters[threadIdx.x] = 0;
  const int t = blockIdx.x / 80;
  const int kc = blockIdx.x % 80;
  const int h = threadIdx.x;
  const float* srcp = W_node + (size_t)t * 1280 * 256 + h;
  bf16_t* dstp = Wt + ((size_t)(t * 256 + h)) * 1280;
#pragma unroll
  for (int k0 = kc * 16; k0 < kc * 16 + 16; k0 += 8) {
    bf16x8 v;
#pragma unroll
    for (int j = 0; j < 8; ++j) v[j] = (bf16_t)srcp[(size_t)(k0 + j) * 256];
    *(bf16x8*)(dstp + k0) = v;
  }
}

// LDS-aggregated bucketing (block-local order preserved -> decent locality).
__global__ __launch_bounds__(256) void bucket_kernel(const int* __restrict__ node_type,
                                                     int* __restrict__ counters,
                                                     int2* __restrict__ buckets) {
  __shared__ int lcnt[18];
  __shared__ int lbase[18];
  const int tid = threadIdx.x;
  if (tid < 18) lcnt[tid] = 0;
  __syncthreads();

  int idx = blockIdx.x * 256 + tid;
  bool active = idx < B_ * NINT;
  int t = 0, key = 0, mypos = 0;
  int2 e;
  int base = 0, nl_cap = 0;
  if (active) {
    int b = idx / NINT;
    int j = idx - b * NINT;
    int l, off;
    if (j >= 781)      { l = 5; off = 781; }
    else if (j >= 156) { l = 4; off = 156; }
    else if (j >= 31)  { l = 3; off = 31; }
    else if (j >= 6)   { l = 2; off = 6; }
    else if (j >= 1)   { l = 1; off = 1; }
    else               { l = 0; off = 0; }
    const int n_tab[6]    = {1, 5, 25, 125, 625, 3125};
    const int nn_tab[6]   = {5, 25, 125, 625, 3125, 15625};
    const int base_tab[6] = {0, 48, 288, 1488, 7488, 37488};
    int n_l = n_tab[l], nn = nn_tab[l];
    t = node_type[idx];
    int i = j - off;
    e.x = b * n_l + i;
    e.y = b * nn + 5 * i;
    base = base_tab[l];
    nl_cap = B_ * n_l;
    key = l * 3 + t;
    mypos = atomicAdd(&lcnt[key], 1);
  }
  __syncthreads();
  if (tid < 18) {
    int c = lcnt[tid];
    lbase[tid] = c ? atomicAdd(&counters[tid], c) : 0;
  }
  __syncthreads();
  if (active) {
    buckets[base + t * nl_cap + lbase[key] + mypos] = e;
  }
}

// For each bucketed parent at (level l, type t, slot s): its 5 children (level
// l+1, node ids 5*node+c) write to G_l row (prefix_t + s), k-slice c. wdest is
// laid out per child level: l1@0(80) l2@80(400) l3@480(2000) l4@2480(10000)
// l5@12480(50000) l6@62480(250000).
__global__ __launch_bounds__(256) void dest_kernel(const int2* __restrict__ buckets,
                                                   const int* __restrict__ counters,
                                                   int* __restrict__ wdest_all) {
  int flat = blockIdx.x * 256 + threadIdx.x;
  if (flat >= 187488) return;
  int l, base, cap, coff;
  if (flat >= 37488)      { l = 5; base = 37488; cap = 50000; coff = 62480; }
  else if (flat >= 7488)  { l = 4; base = 7488;  cap = 10000; coff = 12480; }
  else if (flat >= 1488)  { l = 3; base = 1488;  cap = 2000;  coff = 2480; }
  else if (flat >= 288)   { l = 2; base = 288;   cap = 400;   coff = 480; }
  else if (flat >= 48)    { l = 1; base = 48;    cap = 80;    coff = 80; }
  else                    { l = 0; base = 0;     cap = 16;    coff = 0; }
  int rel = flat - base;
  int t = (rel >= 2 * cap) ? 2 : (rel >= cap ? 1 : 0);
  int s = rel - t * cap;
  const int* c3 = counters + l * 3;
  int cnt = c3[t];
  if (s >= cnt) return;
  int pfx = (t > 0 ? c3[0] : 0) + (t > 1 ? c3[1] : 0);
  int node = buckets[flat].x;
  int grow = (pfx + s) * 5;
  int* wp = wdest_all + coff + 5 * node;
#pragma unroll
  for (int c = 0; c < 5; ++c) wp[c] = grow + c;
}

// MFMA leaf: per wave, A-frags = weights^T (M=h, 8 tiles = half of H per wave),
// B-frags = 16 input rows (N=rows). Bias folded at k=4 (box) / k=16 (sem) with
// B-operand 1.0. Output rows land at gathered slot wd6[row] (G_5 layout).
__global__ __launch_bounds__(256) void leaf_kernel(
    const float* __restrict__ leaf_box, const float* __restrict__ leaf_sem,
    const float* __restrict__ W_box, const float* __restrict__ b_box,
    const float* __restrict__ W_sem, const float* __restrict__ b_sem,
    const int* __restrict__ wd6, bf16_t* __restrict__ f6) {
  const int lane = threadIdx.x & 63;
  const int wave = threadIdx.x >> 6;
  const int q = lane >> 4;
  const int c = lane & 15;
  const int hh = wave & 1;   // h half: tiles hh*8 .. hh*8+7
  const int gw = wave >> 1;  // group slot within block (0,1)

  bf16x8 wsem[8], wbox[8];
#pragma unroll
  for (int T = 0; T < 8; ++T) {
    const int hb = (hh * 8 + T) * 16 + c;  // A-operand M index = lane&15
    bf16x8 a;
#pragma unroll
    for (int j = 0; j < 8; ++j) a[j] = (bf16_t)0.f;
    if (q < 2) {
#pragma unroll
      for (int j = 0; j < 8; ++j) a[j] = (bf16_t)W_sem[(q * 8 + j) * H_ + hb];
    } else if (q == 2) {
      a[0] = (bf16_t)b_sem[hb];  // k=16 bias slot
    }
    wsem[T] = a;
    bf16x8 b;
#pragma unroll
    for (int j = 0; j < 8; ++j) b[j] = (bf16_t)0.f;
    if (q == 0) {
#pragma unroll
      for (int j = 0; j < 4; ++j) b[j] = (bf16_t)W_box[j * H_ + hb];
      b[4] = (bf16_t)b_box[hb];  // k=4 bias slot
    }
    wbox[T] = b;
  }

  const int NG = (B_ * NLEAF) / 16;  // 15625 groups of 16 rows, exact
  const int gstride = gridDim.x * 2;
  for (int g = blockIdx.x * 2 + gw; g < NG; g += gstride) {
    const int row = g * 16 + c;  // B-operand N index = lane&15
    const int wd = wd6[row];
    bf16x8 xs, xb;
#pragma unroll
    for (int j = 0; j < 8; ++j) { xs[j] = (bf16_t)0.f; xb[j] = (bf16_t)0.f; }
    if (q < 2) {
      const float4* sp = (const float4*)(leaf_sem + (size_t)row * 16 + q * 8);
      float4 s0 = sp[0], s1 = sp[1];
      xs[0] = (bf16_t)s0.x; xs[1] = (bf16_t)s0.y; xs[2] = (bf16_t)s0.z; xs[3] = (bf16_t)s0.w;
      xs[4] = (bf16_t)s1.x; xs[5] = (bf16_t)s1.y; xs[6] = (bf16_t)s1.z; xs[7] = (bf16_t)s1.w;
    } else if (q == 2) {
      xs[0] = (bf16_t)1.0f;
    }
    if (q == 0) {
      float4 bx = *(const float4*)(leaf_box + (size_t)row * 4);
      xb[0] = (bf16_t)bx.x; xb[1] = (bf16_t)bx.y; xb[2] = (bf16_t)bx.z; xb[3] = (bf16_t)bx.w;
      xb[4] = (bf16_t)1.0f;
    }
    bf16_t* orow = f6 + (size_t)wd * H_ + hh * 128 + q * 4;
#pragma unroll
    for (int T = 0; T < 8; ++T) {
      f32x4 z = {0.f, 0.f, 0.f, 0.f};
      f32x4 as = __builtin_amdgcn_mfma_f32_16x16x32_bf16(wsem[T], xs, z, 0, 0, 0);
      f32x4 ab = __builtin_amdgcn_mfma_f32_16x16x32_bf16(wbox[T], xb, z, 0, 0, 0);
      bf16x4 o;
#pragma unroll
      for (int r = 0; r < 4; ++r)
        o[r] = (bf16_t)(fmaxf(as[r], 0.f) + fmaxf(ab[r], 0.f));
      *(bf16x4*)(orow + T * 16) = o;
    }
  }
}

// 128x128 tile, K=1280 in 40 stages of BK=32. A-read is now a CONTIGUOUS stream
// (rows pfx+tile0..+127 of G_l). 3 LDS buffers, DMA 2 stages ahead, counted
// vmcnt(4) + raw s_barrier. Chunk swizzle p = q ^ ((row>>1)&3) on stage-source
// and frag-read (conflict-free, LDS linear). Output row -> wdest slot of G_{l-1}
// (or f0 when wdest==null). setprio(1) around MFMA cluster.
__global__ __launch_bounds__(256) void level_kernel(
    const bf16_t* __restrict__ src, bf16_t* __restrict__ dst,
    const int2* __restrict__ bucket, const int* __restrict__ counters,
    const bf16_t* __restrict__ Wt, const float* __restrict__ b_node,
    const float* __restrict__ ibox, const float* __restrict__ W_box,
    const float* __restrict__ b_box, const int* __restrict__ wdest,
    int n_l, int off_l, int cap) {
  const int t = blockIdx.y;
  const int cnt = counters[t];
  const int tile0 = blockIdx.x * 128;
  if (tile0 >= cnt) return;
  const int pfx = (t > 0 ? counters[0] : 0) + (t > 1 ? counters[1] : 0);
  const int nblk = blockIdx.z;
  const int2* rd = bucket + (size_t)t * cap;

  __shared__ __align__(16) bf16_t Asm[3][128][32];  // 8 KB per buf
  __shared__ __align__(16) bf16_t Bsm[3][128][32];

  const int tid = threadIdx.x;
  const int lane = tid & 63;
  const int wave = tid >> 6;
  const int wm = wave & 1, wn = wave >> 1;
  const int quad = lane >> 4;
  const int l15 = lane & 15;

  // staging: instr i covers rows wave*32 + i*16 + r4 (r4=lane>>2); LDS dest is
  // linear (lane*16B), so physical chunk c4 holds GLOBAL chunk c4 ^ ((r4>>1)&3).
  const int r4 = lane >> 2;
  const int c4 = lane & 3;
  const int gch = c4 ^ ((r4 >> 1) & 3);
  const bf16_t* wsrc = Wt + ((size_t)t * 256 + nblk * 128) * 1280;
  const bf16_t* asrc = src + (size_t)pfx * 1280;
  const bf16_t* aptr[2];
  const bf16_t* bptr[2];
#pragma unroll
  for (int i = 0; i < 2; ++i) {
    int r = wave * 32 + i * 16 + r4;
    int rowi = tile0 + r;
    if (rowi >= cnt) rowi = cnt - 1;
    aptr[i] = asrc + (size_t)rowi * 1280 + gch * 8;
    bptr[i] = wsrc + (size_t)r * 1280 + gch * 8;
  }

  f32x4 acc[4][4];
#pragma unroll
  for (int i = 0; i < 4; ++i)
#pragma unroll
    for (int j = 0; j < 4; ++j) acc[i][j] = (f32x4){0.f, 0.f, 0.f, 0.f};

  // frag read: logical chunk = quad, physical = quad ^ ((l15>>1)&3)
  const int pcs = (quad ^ ((l15 >> 1) & 3)) * 8;

#define STAGE(buf, ks)                                  \
  {                                                     \
    const int ko = (ks) * 32;                           \
    bf16_t* la = &Asm[buf][0][0] + wave * 1024;         \
    bf16_t* lb = &Bsm[buf][0][0] + wave * 1024;         \
    gl2lds16(aptr[0] + ko, la);                         \
    gl2lds16(aptr[1] + ko, la + 512);                   \
    gl2lds16(bptr[0] + ko, lb);                         \
    gl2lds16(bptr[1] + ko, lb + 512);                   \
  }

#define FRAGS_AND_MFMA(bufv)                                                  \
  {                                                                           \
    bf16x8 af[4], bfr[4];                                                     \
    _Pragma("unroll") for (int am = 0; am < 4; ++am)                          \
        af[am] = *(const bf16x8*)(&Asm[bufv][wm * 64 + am * 16 + l15][pcs]);  \
    _Pragma("unroll") for (int bn = 0; bn < 4; ++bn)                          \
        bfr[bn] = *(const bf16x8*)(&Bsm[bufv][wn * 64 + bn * 16 + l15][pcs]); \
    __builtin_amdgcn_s_setprio(1);                                            \
    _Pragma("unroll") for (int am = 0; am < 4; ++am)                          \
        _Pragma("unroll") for (int bn = 0; bn < 4; ++bn)                      \
            acc[am][bn] = __builtin_amdgcn_mfma_f32_16x16x32_bf16(            \
                af[am], bfr[bn], acc[am][bn], 0, 0, 0);                       \
    __builtin_amdgcn_s_setprio(0);                                            \
  }

  STAGE(0, 0)
  STAGE(1, 1)
  int buf = 0, nxb = 2;
  for (int ks = 0; ks < 38; ++ks) {
    // steady state: 8 DMAs outstanding (stages ks, ks+1); retire stage ks's 4.
    asm volatile("s_waitcnt vmcnt(4)" ::: "memory");
    __builtin_amdgcn_s_barrier();
    {
      bf16x8 af[4], bfr[4];
#pragma unroll
      for (int am = 0; am < 4; ++am)
        af[am] = *(const bf16x8*)(&Asm[buf][wm * 64 + am * 16 + l15][pcs]);
#pragma unroll
      for (int bn = 0; bn < 4; ++bn)
        bfr[bn] = *(const bf16x8*)(&Bsm[buf][wn * 64 + bn * 16 + l15][pcs]);
      STAGE(nxb, ks + 2)  // overwrites buf read at ks-1: safe after this barrier
      __builtin_amdgcn_s_setprio(1);
#pragma unroll
      for (int am = 0; am < 4; ++am)
#pragma unroll
        for (int bn = 0; bn < 4; ++bn)
          acc[am][bn] = __builtin_amdgcn_mfma_f32_16x16x32_bf16(af[am], bfr[bn], acc[am][bn], 0, 0, 0);
      __builtin_amdgcn_s_setprio(0);
    }
    buf = (buf == 2) ? 0 : buf + 1;
    nxb = (nxb == 2) ? 0 : nxb + 1;
  }
  // tail: ks=38 (stage 39 still in flight), ks=39 (full drain)
  asm volatile("s_waitcnt vmcnt(4)" ::: "memory");
  __builtin_amdgcn_s_barrier();
  FRAGS_AND_MFMA(buf)
  buf = (buf == 2) ? 0 : buf + 1;
  asm volatile("s_waitcnt vmcnt(0)" ::: "memory");
  __builtin_amdgcn_s_barrier();
  FRAGS_AND_MFMA(buf)
#undef FRAGS_AND_MFMA
#undef STAGE

  // Epilogue. C/D: col = l15 (n), row = quad*4 + reg (m).
  float wbv[4][6];
#pragma unroll
  for (int bn = 0; bn < 4; ++bn) {
    int col = nblk * 128 + wn * 64 + bn * 16 + l15;
    wbv[bn][0] = W_box[col];
    wbv[bn][1] = W_box[H_ + col];
    wbv[bn][2] = W_box[2 * H_ + col];
    wbv[bn][3] = W_box[3 * H_ + col];
    wbv[bn][4] = b_box[col];
    wbv[bn][5] = b_node[t * H_ + col];
  }
#pragma unroll
  for (int am = 0; am < 4; ++am) {
    size_t obase[4]; float4 bxv[4]; bool valid[4];
#pragma unroll
    for (int r = 0; r < 4; ++r) {
      int gidx = tile0 + wm * 64 + am * 16 + quad * 4 + r;
      valid[r] = (gidx < cnt);
      int ic = valid[r] ? gidx : (cnt - 1);
      int orw = rd[ic].x;
      obase[r] = (size_t)(wdest ? wdest[orw] : orw) * H_;
      int b = orw / n_l;
      int i = orw - b * n_l;
      bxv[r] = *(const float4*)(ibox + ((size_t)b * NINT + off_l + i) * 4);
    }
#pragma unroll
    for (int bn = 0; bn < 4; ++bn) {
      int col = nblk * 128 + wn * 64 + bn * 16 + l15;
#pragma unroll
      for (int r = 0; r < 4; ++r) {
        if (!valid[r]) continue;
        float y = fmaxf(acc[am][bn][r] + wbv[bn][5], 0.f);
        float be = fmaf(wbv[bn][0], bxv[r].x,
                   fmaf(wbv[bn][1], bxv[r].y,
                   fmaf(wbv[bn][2], bxv[r].z,
                   fmaf(wbv[bn][3], bxv[r].w, wbv[bn][4]))));
        be = fmaxf(be, 0.f);
        dst[obase[r] + col] = (bf16_t)(y + be);
      }
    }
  }
}

__global__ __launch_bounds__(256) void head_kernel(
    const bf16_t* __restrict__ f0, const float* __restrict__ eps,
    const float* __restrict__ W1, const float* __restrict__ b1,
    const float* __restrict__ Wmu, const float* __restrict__ bmu,
    const float* __restrict__ Wvar, const float* __restrict__ bvar,
    float* __restrict__ out) {
  __shared__ float root[256];
  __shared__ float enc[256];
  int b = blockIdx.x, h = threadIdx.x;
  root[h] = (float)f0[b * H_ + h];
  __syncthreads();
  float a = b1[h];
  for (int k = 0; k < 256; ++k) a = fmaf(root[k], W1[k * H_ + h], a);
  enc[h] = fmaxf(a, 0.f);
  __syncthreads();
  float m = bmu[h], lv = bvar[h];
  for (int k = 0; k < 256; ++k) {
    float e = enc[k];
    m = fmaf(e, Wmu[k * H_ + h], m);
    lv = fmaf(e, Wvar[k * H_ + h], lv);
  }
  float stdv = expf(0.5f * lv);
  float kld = 1.f + lv - m * m - expf(lv);
  out[b * 512 + h] = eps[b * H_ + h] * stdv + m;
  out[b * 512 + 256 + h] = kld;
}

extern "C" void kernel_launch(void* const* d_in, const int* in_sizes, int n_in,
                              void* d_out, int out_size, void* d_ws, size_t ws_size,
                              hipStream_t stream) {
  const float* leaf_box     = (const float*)d_in[0];
  const float* leaf_sem     = (const float*)d_in[1];
  const float* internal_box = (const float*)d_in[2];
  const int*   node_type    = (const int*)d_in[3];
  const float* eps          = (const float*)d_in[4];
  const float* W_box        = (const float*)d_in[5];
  const float* b_box        = (const float*)d_in[6];
  const float* W_sem        = (const float*)d_in[7];
  const float* b_sem        = (const float*)d_in[8];
  const float* W_node       = (const float*)d_in[9];
  const float* b_node       = (const float*)d_in[10];
  const float* W1           = (const float*)d_in[11];
  const float* b1           = (const float*)d_in[12];
  const float* Wmu          = (const float*)d_in[13];
  const float* bmu          = (const float*)d_in[14];
  const float* Wvar         = (const float*)d_in[15];
  const float* bvar         = (const float*)d_in[16];
  float* out = (float*)d_out;

  char* p = (char*)d_ws;
  auto alloc = [&](size_t bytes) {
    char* r = p;
    p += (bytes + 255) & ~(size_t)255;
    return r;
  };
  bf16_t* Wt = (bf16_t*)alloc((size_t)3 * 256 * 1280 * 2);
  const int n_tab[7] = {1, 5, 25, 125, 625, 3125, 15625};
  // f[0] = root features (node order); f[l+1] = G_l (gathered children of level l)
  bf16_t* f[7];
  for (int l = 0; l <= 6; ++l) f[l] = (bf16_t*)alloc((size_t)B_ * n_tab[l] * H_ * 2);
  int* counters = (int*)alloc(18 * 4);
  int2* buckets = (int2*)alloc((size_t)187488 * 8);
  int* wdest_all = (int*)alloc((size_t)312480 * 4);

  hipLaunchKernelGGL(prep_kernel, dim3(240), dim3(256), 0, stream, W_node, Wt, counters);
  hipLaunchKernelGGL(bucket_kernel, dim3((B_ * NINT + 255) / 256), dim3(256), 0, stream,
                     node_type, counters, buckets);
  hipLaunchKernelGGL(dest_kernel, dim3((187488 + 255) / 256), dim3(256), 0, stream,
                     buckets, counters, wdest_all);
  hipLaunchKernelGGL(leaf_kernel, dim3(1024), dim3(256), 0, stream,
                     leaf_box, leaf_sem, W_box, b_box, W_sem, b_sem,
                     wdest_all + 62480, f[6]);

  const int lvl_base[6] = {0, 48, 288, 1488, 7488, 37488};
  const int off_tab[6]  = {0, 1, 6, 31, 156, 781};
  const int woff[6]     = {0, 0, 80, 480, 2480, 12480};  // wdest offset for level l (l>=1)
  for (int l = 5; l >= 0; --l) {
    int cap = B_ * n_tab[l];
    int tiles = (cap + 127) / 128;
    const int* wdp = (l >= 1) ? (wdest_all + woff[l]) : nullptr;
    hipLaunchKernelGGL(level_kernel, dim3(tiles, 3, 2), dim3(256), 0, stream,
                       f[l + 1], f[l], buckets + lvl_base[l], counters + l * 3,
                       Wt, b_node, internal_box, W_box, b_box, wdp,
                       n_tab[l], off_tab[l], cap);
  }
  hipLaunchKernelGGL(head_kernel, dim3(16), dim3(256), 0, stream,
                     f[0], eps, W1, b1, Wmu, bmu, Wvar, bvar, out);
}

// Round 4
// 373.466 us; speedup vs baseline: 1.0698x; 1.0698x over previous
//
#include <hip/hip_runtime.h>

// RecursiveEncoder on MI355X. B=16, H=256, S=16, C=5, L=6, N_LEAF=15625, N_INT=3906.
// R9: K-PANEL LAYOUT. R8 showed compulsory-only FETCH at 31% BW: row-major G
//     makes each stage a 64B-granular / 2560B-stride walk (~2 TB/s regime).
//     G and Wt are now stored [panel=128 rows][ks][row][64B] with the 16B-chunk
//     XOR pre-applied at write time: a stage's A/B fetch = contiguous 8KB slab,
//     per-DMA-instr 1KB contiguous, per-block sequential 320KB stream. Type
//     prefixes rounded to 128 (panel-aligned); pad rows feed discarded outputs.
//     Leaf inverted to slot-order (rsrc from dest_kernel): 128MB of leaf writes
//     become sequential; gathered inputs are L3-resident (23MB). Pipeline,
//     swizzle, vmcnt schedule unchanged from R8 (0 conflicts).

#define B_ 16
#define H_ 256
#define NLEAF 15625
#define NINT 3906
#define RND128(x) (((x) + 127) & ~127)

typedef __bf16 bf16_t;
typedef bf16_t bf16x8 __attribute__((ext_vector_type(8)));
typedef bf16_t bf16x4 __attribute__((ext_vector_type(4)));
typedef float f32x4 __attribute__((ext_vector_type(4)));

__device__ __forceinline__ void gl2lds16(const bf16_t* g, bf16_t* l) {
  __builtin_amdgcn_global_load_lds((const __attribute__((address_space(1))) void*)g,
                                   (__attribute__((address_space(3))) void*)l,
                                   16, 0, 0);
}

// Wt K-panel layout: panel (t*2+half) of 128 h-rows; elem (h,k) at
// panel*40*4096 + (k>>5)*4096 + (h&127)*32 + (chunk^swz)*8 + (k&7).
__global__ __launch_bounds__(256) void prep_kernel(const float* __restrict__ W_node,
                                                   bf16_t* __restrict__ Wt,
                                                   int* __restrict__ counters) {
  if (blockIdx.x == 0 && threadIdx.x < 18) counters[threadIdx.x] = 0;
  const int t = blockIdx.x / 80;
  const int kc = blockIdx.x % 80;
  const int h = threadIdx.x;
  const int half = h >> 7, r = h & 127;
  const int sw = (r >> 1) & 3;
  const float* srcp = W_node + (size_t)t * 1280 * 256 + h;
  bf16_t* base = Wt + ((size_t)(t * 2 + half) * 40) * 4096 + r * 32;
#pragma unroll
  for (int k0 = kc * 16; k0 < kc * 16 + 16; k0 += 8) {
    bf16x8 v;
#pragma unroll
    for (int j = 0; j < 8; ++j) v[j] = (bf16_t)srcp[(size_t)(k0 + j) * 256];
    const int ks = k0 >> 5;
    const int q = (k0 >> 3) & 3;
    *(bf16x8*)(base + (size_t)ks * 4096 + ((q ^ sw) << 3)) = v;
  }
}

// LDS-aggregated bucketing (block-local order preserved -> decent locality).
__global__ __launch_bounds__(256) void bucket_kernel(const int* __restrict__ node_type,
                                                     int* __restrict__ counters,
                                                     int2* __restrict__ buckets) {
  __shared__ int lcnt[18];
  __shared__ int lbase[18];
  const int tid = threadIdx.x;
  if (tid < 18) lcnt[tid] = 0;
  __syncthreads();

  int idx = blockIdx.x * 256 + tid;
  bool active = idx < B_ * NINT;
  int t = 0, key = 0, mypos = 0;
  int2 e;
  int base = 0, nl_cap = 0;
  if (active) {
    int b = idx / NINT;
    int j = idx - b * NINT;
    int l, off;
    if (j >= 781)      { l = 5; off = 781; }
    else if (j >= 156) { l = 4; off = 156; }
    else if (j >= 31)  { l = 3; off = 31; }
    else if (j >= 6)   { l = 2; off = 6; }
    else if (j >= 1)   { l = 1; off = 1; }
    else               { l = 0; off = 0; }
    const int n_tab[6]    = {1, 5, 25, 125, 625, 3125};
    const int nn_tab[6]   = {5, 25, 125, 625, 3125, 15625};
    const int base_tab[6] = {0, 48, 288, 1488, 7488, 37488};
    int n_l = n_tab[l], nn = nn_tab[l];
    t = node_type[idx];
    int i = j - off;
    e.x = b * n_l + i;
    e.y = b * nn + 5 * i;
    base = base_tab[l];
    nl_cap = B_ * n_l;
    key = l * 3 + t;
    mypos = atomicAdd(&lcnt[key], 1);
  }
  __syncthreads();
  if (tid < 18) {
    int c = lcnt[tid];
    lbase[tid] = c ? atomicAdd(&counters[tid], c) : 0;
  }
  __syncthreads();
  if (active) {
    buckets[base + t * nl_cap + lbase[key] + mypos] = e;
  }
}

// Parent at (level l, type t, bucket slot s) owns G_l row R = pfxr_t + s
// (pfxr = 128-rounded type prefix). For l<5: children (level l+1, id 5*node+c)
// get wdest = R*8+c. For l=5: rsrc[R*5+c] = leaf row feeding that chunk.
__global__ __launch_bounds__(256) void dest_kernel(const int2* __restrict__ buckets,
                                                   const int* __restrict__ counters,
                                                   int* __restrict__ wdest_all,
                                                   int* __restrict__ rsrc6) {
  int flat = blockIdx.x * 256 + threadIdx.x;
  if (flat >= 187488) return;
  int l, base, cap, coff;
  if (flat >= 37488)      { l = 5; base = 37488; cap = 50000; coff = 0; }
  else if (flat >= 7488)  { l = 4; base = 7488;  cap = 10000; coff = 12480; }
  else if (flat >= 1488)  { l = 3; base = 1488;  cap = 2000;  coff = 2480; }
  else if (flat >= 288)   { l = 2; base = 288;   cap = 400;   coff = 480; }
  else if (flat >= 48)    { l = 1; base = 48;    cap = 80;    coff = 80; }
  else                    { l = 0; base = 0;     cap = 16;    coff = 0; }
  int rel = flat - base;
  int t = (rel >= 2 * cap) ? 2 : (rel >= cap ? 1 : 0);
  int s = rel - t * cap;
  const int* c3 = counters + l * 3;
  if (s >= c3[t]) return;
  int pfxr = (t > 0 ? RND128(c3[0]) : 0) + (t > 1 ? RND128(c3[1]) : 0);
  int R = pfxr + s;
  int2 e = buckets[flat];
  if (l == 5) {
    int* rp = rsrc6 + 5 * R;
#pragma unroll
    for (int c = 0; c < 5; ++c) rp[c] = e.y + c;
  } else {
    int* wp = wdest_all + coff + 5 * e.x;
#pragma unroll
    for (int c = 0; c < 5; ++c) wp[c] = (R << 3) + c;
  }
}

// MFMA leaf, slot-ordered: wave handles 16 consecutive G_5 chunk-slots ci
// (R=ci/5, child c5=ci%5); input leaf row = rsrc[ci] (gathered; inputs are
// L3-resident). Writes land in K-panel layout -> sequential 128MB.
__global__ __launch_bounds__(256) void leaf_kernel(
    const float* __restrict__ leaf_box, const float* __restrict__ leaf_sem,
    const float* __restrict__ W_box, const float* __restrict__ b_box,
    const float* __restrict__ W_sem, const float* __restrict__ b_sem,
    const int* __restrict__ rsrc, bf16_t* __restrict__ g5) {
  const int lane = threadIdx.x & 63;
  const int wave = threadIdx.x >> 6;
  const int q = lane >> 4;
  const int c = lane & 15;
  const int hh = wave & 1;   // h half: tiles hh*8 .. hh*8+7
  const int gw = wave >> 1;  // group slot within block (0,1)

  bf16x8 wsem[8], wbox[8];
#pragma unroll
  for (int T = 0; T < 8; ++T) {
    const int hb = (hh * 8 + T) * 16 + c;  // A-operand M index = lane&15
    bf16x8 a;
#pragma unroll
    for (int j = 0; j < 8; ++j) a[j] = (bf16_t)0.f;
    if (q < 2) {
#pragma unroll
      for (int j = 0; j < 8; ++j) a[j] = (bf16_t)W_sem[(q * 8 + j) * H_ + hb];
    } else if (q == 2) {
      a[0] = (bf16_t)b_sem[hb];  // k=16 bias slot
    }
    wsem[T] = a;
    bf16x8 b;
#pragma unroll
    for (int j = 0; j < 8; ++j) b[j] = (bf16_t)0.f;
    if (q == 0) {
#pragma unroll
      for (int j = 0; j < 4; ++j) b[j] = (bf16_t)W_box[j * H_ + hb];
      b[4] = (bf16_t)b_box[hb];  // k=4 bias slot
    }
    wbox[T] = b;
  }

  const int NG2 = 15705;  // (50000+256)*5 / 16 slot-groups (covers pad rows)
  const int gstride = gridDim.x * 2;
  for (int g = blockIdx.x * 2 + gw; g < NG2; g += gstride) {
    const int ci = g * 16 + c;
    int row = rsrc[ci];
    row = ((unsigned)row < (unsigned)(B_ * NLEAF)) ? row : 0;  // pad slots: any valid row
    const int R = ci / 5;
    const int c5 = ci - R * 5;
    bf16x8 xs, xb;
#pragma unroll
    for (int j = 0; j < 8; ++j) { xs[j] = (bf16_t)0.f; xb[j] = (bf16_t)0.f; }
    if (q < 2) {
      const float4* sp = (const float4*)(leaf_sem + (size_t)row * 16 + q * 8);
      float4 s0 = sp[0], s1 = sp[1];
      xs[0] = (bf16_t)s0.x; xs[1] = (bf16_t)s0.y; xs[2] = (bf16_t)s0.z; xs[3] = (bf16_t)s0.w;
      xs[4] = (bf16_t)s1.x; xs[5] = (bf16_t)s1.y; xs[6] = (bf16_t)s1.z; xs[7] = (bf16_t)s1.w;
    } else if (q == 2) {
      xs[0] = (bf16_t)1.0f;
    }
    if (q == 0) {
      float4 bx = *(const float4*)(leaf_box + (size_t)row * 4);
      xb[0] = (bf16_t)bx.x; xb[1] = (bf16_t)bx.y; xb[2] = (bf16_t)bx.z; xb[3] = (bf16_t)bx.w;
      xb[4] = (bf16_t)1.0f;
    }
    const int rr = R & 127;
    const int sw = (rr >> 1) & 3;
    bf16_t* obase = g5 + (size_t)(R >> 7) * 163840 + rr * 32;
#pragma unroll
    for (int T = 0; T < 8; ++T) {
      f32x4 z = {0.f, 0.f, 0.f, 0.f};
      f32x4 as = __builtin_amdgcn_mfma_f32_16x16x32_bf16(wsem[T], xs, z, 0, 0, 0);
      f32x4 ab = __builtin_amdgcn_mfma_f32_16x16x32_bf16(wbox[T], xb, z, 0, 0, 0);
      bf16x4 o;
#pragma unroll
      for (int r = 0; r < 4; ++r)
        o[r] = (bf16_t)(fmaxf(as[r], 0.f) + fmaxf(ab[r], 0.f));
      // col = hh*128 + q*4 + T*16; e = c5*256+col -> K-panel address
      const int ks = c5 * 8 + hh * 4 + (T >> 1);
      const int pc = (((T & 1) << 1) | (q >> 1)) ^ sw;
      *(bf16x4*)(obase + (size_t)ks * 4096 + (pc << 3) + ((q & 1) << 2)) = o;
    }
  }
}

// 128x128 tile, K=1280 in 40 stages of BK=32. A and B fetched as contiguous
// 8KB K-panel slabs (1KB per DMA instr). 3 LDS buffers, DMA 2 stages ahead,
// counted vmcnt(4) + raw s_barrier. Frag-read XOR matches the pre-applied
// store-side swizzle (conflict-free). setprio(1) around MFMA cluster.
__global__ __launch_bounds__(256) void level_kernel(
    const bf16_t* __restrict__ src, bf16_t* __restrict__ dst,
    const int2* __restrict__ bucket, const int* __restrict__ counters,
    const bf16_t* __restrict__ Wt, const float* __restrict__ b_node,
    const float* __restrict__ ibox, const float* __restrict__ W_box,
    const float* __restrict__ b_box, const int* __restrict__ wdest,
    int n_l, int off_l, int cap) {
  const int t = blockIdx.y;
  const int cnt = counters[t];
  const int tile0 = blockIdx.x * 128;
  if (tile0 >= cnt) return;
  const int pfxr = (t > 0 ? RND128(counters[0]) : 0) + (t > 1 ? RND128(counters[1]) : 0);
  const int nblk = blockIdx.z;
  const int2* rd = bucket + (size_t)t * cap;

  __shared__ __align__(16) bf16_t Asm[3][128][32];  // 8 KB per buf
  __shared__ __align__(16) bf16_t Bsm[3][128][32];

  const int tid = threadIdx.x;
  const int lane = tid & 63;
  const int wave = tid >> 6;
  const int wm = wave & 1, wn = wave >> 1;
  const int quad = lane >> 4;
  const int l15 = lane & 15;

  // A slab: panel (pfxr+tile0)/128, 8KB per stage, linear copy (pre-swizzled).
  const bf16_t* ga0 = src + (size_t)(pfxr + tile0) * 1280 + wave * 1024 + (lane << 3);
  const bf16_t* gb0 = Wt + ((size_t)(t * 2 + nblk) * 40) * 4096 + wave * 1024 + (lane << 3);

  f32x4 acc[4][4];
#pragma unroll
  for (int i = 0; i < 4; ++i)
#pragma unroll
    for (int j = 0; j < 4; ++j) acc[i][j] = (f32x4){0.f, 0.f, 0.f, 0.f};

  // frag read: logical chunk = quad, physical = quad ^ ((l15>>1)&3)
  const int pcs = (quad ^ ((l15 >> 1) & 3)) * 8;

#define STAGE(buf, ks)                                  \
  {                                                     \
    const bf16_t* ga = ga0 + (ks) * 4096;               \
    const bf16_t* gb = gb0 + (ks) * 4096;               \
    bf16_t* la = &Asm[buf][0][0] + wave * 1024;         \
    bf16_t* lb = &Bsm[buf][0][0] + wave * 1024;         \
    gl2lds16(ga, la);                                   \
    gl2lds16(ga + 512, la + 512);                       \
    gl2lds16(gb, lb);                                   \
    gl2lds16(gb + 512, lb + 512);                       \
  }

#define FRAGS_AND_MFMA(bufv)                                                  \
  {                                                                           \
    bf16x8 af[4], bfr[4];                                                     \
    _Pragma("unroll") for (int am = 0; am < 4; ++am)                          \
        af[am] = *(const bf16x8*)(&Asm[bufv][wm * 64 + am * 16 + l15][pcs]);  \
    _Pragma("unroll") for (int bn = 0; bn < 4; ++bn)                          \
        bfr[bn] = *(const bf16x8*)(&Bsm[bufv][wn * 64 + bn * 16 + l15][pcs]); \
    __builtin_amdgcn_s_setprio(1);                                            \
    _Pragma("unroll") for (int am = 0; am < 4; ++am)                          \
        _Pragma("unroll") for (int bn = 0; bn < 4; ++bn)                      \
            acc[am][bn] = __builtin_amdgcn_mfma_f32_16x16x32_bf16(            \
                af[am], bfr[bn], acc[am][bn], 0, 0, 0);                       \
    __builtin_amdgcn_s_setprio(0);                                            \
  }

  STAGE(0, 0)
  STAGE(1, 1)
  int buf = 0, nxb = 2;
  for (int ks = 0; ks < 38; ++ks) {
    // steady state: 8 DMAs outstanding (stages ks, ks+1); retire stage ks's 4.
    asm volatile("s_waitcnt vmcnt(4)" ::: "memory");
    __builtin_amdgcn_s_barrier();
    {
      bf16x8 af[4], bfr[4];
#pragma unroll
      for (int am = 0; am < 4; ++am)
        af[am] = *(const bf16x8*)(&Asm[buf][wm * 64 + am * 16 + l15][pcs]);
#pragma unroll
      for (int bn = 0; bn < 4; ++bn)
        bfr[bn] = *(const bf16x8*)(&Bsm[buf][wn * 64 + bn * 16 + l15][pcs]);
      STAGE(nxb, ks + 2)  // overwrites buf read at ks-1: safe after this barrier
      __builtin_amdgcn_s_setprio(1);
#pragma unroll
      for (int am = 0; am < 4; ++am)
#pragma unroll
        for (int bn = 0; bn < 4; ++bn)
          acc[am][bn] = __builtin_amdgcn_mfma_f32_16x16x32_bf16(af[am], bfr[bn], acc[am][bn], 0, 0, 0);
      __builtin_amdgcn_s_setprio(0);
    }
    buf = (buf == 2) ? 0 : buf + 1;
    nxb = (nxb == 2) ? 0 : nxb + 1;
  }
  // tail: ks=38 (stage 39 still in flight), ks=39 (full drain)
  asm volatile("s_waitcnt vmcnt(4)" ::: "memory");
  __builtin_amdgcn_s_barrier();
  FRAGS_AND_MFMA(buf)
  buf = (buf == 2) ? 0 : buf + 1;
  asm volatile("s_waitcnt vmcnt(0)" ::: "memory");
  __builtin_amdgcn_s_barrier();
  FRAGS_AND_MFMA(buf)
#undef FRAGS_AND_MFMA
#undef STAGE

  // Epilogue. C/D: col = l15 (n), row = quad*4 + reg (m).
  float wbv[4][6];
#pragma unroll
  for (int bn = 0; bn < 4; ++bn) {
    int col = nblk * 128 + wn * 64 + bn * 16 + l15;
    wbv[bn][0] = W_box[col];
    wbv[bn][1] = W_box[H_ + col];
    wbv[bn][2] = W_box[2 * H_ + col];
    wbv[bn][3] = W_box[3 * H_ + col];
    wbv[bn][4] = b_box[col];
    wbv[bn][5] = b_node[t * H_ + col];
  }
#pragma unroll
  for (int am = 0; am < 4; ++am) {
    int orw_[4]; float4 bxv[4]; bool valid[4];
#pragma unroll
    for (int r = 0; r < 4; ++r) {
      int gidx = tile0 + wm * 64 + am * 16 + quad * 4 + r;
      valid[r] = (gidx < cnt);
      int ic = valid[r] ? gidx : (cnt - 1);
      int orw = rd[ic].x;
      orw_[r] = orw;
      int b = orw / n_l;
      int i = orw - b * n_l;
      bxv[r] = *(const float4*)(ibox + ((size_t)b * NINT + off_l + i) * 4);
    }
    if (wdest) {
      size_t ob[4]; int sw_[4];
#pragma unroll
      for (int r = 0; r < 4; ++r) {
        int wd = wdest[orw_[r]];
        int R = wd >> 3, cc = wd & 7;
        int rr = R & 127;
        ob[r] = (size_t)(R >> 7) * 163840 + (size_t)cc * 32768 + (size_t)rr * 32;
        sw_[r] = (rr >> 1) & 3;
      }
#pragma unroll
      for (int bn = 0; bn < 4; ++bn) {
        int col = nblk * 128 + wn * 64 + bn * 16 + l15;
        int kc2 = col >> 5, qq = (col >> 3) & 3, ww = col & 7;
#pragma unroll
        for (int r = 0; r < 4; ++r) {
          if (!valid[r]) continue;
          float y = fmaxf(acc[am][bn][r] + wbv[bn][5], 0.f);
          float be = fmaf(wbv[bn][0], bxv[r].x,
                     fmaf(wbv[bn][1], bxv[r].y,
                     fmaf(wbv[bn][2], bxv[r].z,
                     fmaf(wbv[bn][3], bxv[r].w, wbv[bn][4]))));
          be = fmaxf(be, 0.f);
          dst[ob[r] + (size_t)kc2 * 4096 + ((qq ^ sw_[r]) << 3) + ww] = (bf16_t)(y + be);
        }
      }
    } else {
#pragma unroll
      for (int bn = 0; bn < 4; ++bn) {
        int col = nblk * 128 + wn * 64 + bn * 16 + l15;
#pragma unroll
        for (int r = 0; r < 4; ++r) {
          if (!valid[r]) continue;
          float y = fmaxf(acc[am][bn][r] + wbv[bn][5], 0.f);
          float be = fmaf(wbv[bn][0], bxv[r].x,
                     fmaf(wbv[bn][1], bxv[r].y,
                     fmaf(wbv[bn][2], bxv[r].z,
                     fmaf(wbv[bn][3], bxv[r].w, wbv[bn][4]))));
          be = fmaxf(be, 0.f);
          dst[(size_t)orw_[r] * H_ + col] = (bf16_t)(y + be);
        }
      }
    }
  }
}

__global__ __launch_bounds__(256) void head_kernel(
    const bf16_t* __restrict__ f0, const float* __restrict__ eps,
    const float* __restrict__ W1, const float* __restrict__ b1,
    const float* __restrict__ Wmu, const float* __restrict__ bmu,
    const float* __restrict__ Wvar, const float* __restrict__ bvar,
    float* __restrict__ out) {
  __shared__ float root[256];
  __shared__ float enc[256];
  int b = blockIdx.x, h = threadIdx.x;
  root[h] = (float)f0[b * H_ + h];
  __syncthreads();
  float a = b1[h];
  for (int k = 0; k < 256; ++k) a = fmaf(root[k], W1[k * H_ + h], a);
  enc[h] = fmaxf(a, 0.f);
  __syncthreads();
  float m = bmu[h], lv = bvar[h];
  for (int k = 0; k < 256; ++k) {
    float e = enc[k];
    m = fmaf(e, Wmu[k * H_ + h], m);
    lv = fmaf(e, Wvar[k * H_ + h], lv);
  }
  float stdv = expf(0.5f * lv);
  float kld = 1.f + lv - m * m - expf(lv);
  out[b * 512 + h] = eps[b * H_ + h] * stdv + m;
  out[b * 512 + 256 + h] = kld;
}

extern "C" void kernel_launch(void* const* d_in, const int* in_sizes, int n_in,
                              void* d_out, int out_size, void* d_ws, size_t ws_size,
                              hipStream_t stream) {
  const float* leaf_box     = (const float*)d_in[0];
  const float* leaf_sem     = (const float*)d_in[1];
  const float* internal_box = (const float*)d_in[2];
  const int*   node_type    = (const int*)d_in[3];
  const float* eps          = (const float*)d_in[4];
  const float* W_box        = (const float*)d_in[5];
  const float* b_box        = (const float*)d_in[6];
  const float* W_sem        = (const float*)d_in[7];
  const float* b_sem        = (const float*)d_in[8];
  const float* W_node       = (const float*)d_in[9];
  const float* b_node       = (const float*)d_in[10];
  const float* W1           = (const float*)d_in[11];
  const float* b1           = (const float*)d_in[12];
  const float* Wmu          = (const float*)d_in[13];
  const float* bmu          = (const float*)d_in[14];
  const float* Wvar         = (const float*)d_in[15];
  const float* bvar         = (const float*)d_in[16];
  float* out = (float*)d_out;

  char* p = (char*)d_ws;
  auto alloc = [&](size_t bytes) {
    char* r = p;
    p += (bytes + 255) & ~(size_t)255;
    return r;
  };
  const int n_tab[6] = {1, 5, 25, 125, 625, 3125};
  bf16_t* Wt = (bf16_t*)alloc((size_t)3 * 2 * 40 * 4096 * 2);  // 1.97 MB, K-panel
  bf16_t* f0 = (bf16_t*)alloc((size_t)B_ * H_ * 2);
  bf16_t* G[6];  // G[l] = K-panel child-concat matrix for level-l parents
  for (int l = 0; l <= 5; ++l)
    G[l] = (bf16_t*)alloc(((size_t)B_ * n_tab[l] + 384) * 1280 * 2);
  int* counters  = (int*)alloc(18 * 4);
  int2* buckets  = (int2*)alloc((size_t)187488 * 8);
  int* wdest_all = (int*)alloc((size_t)62480 * 4);
  int* rsrc6     = (int*)alloc((size_t)251280 * 4);

  hipLaunchKernelGGL(prep_kernel, dim3(240), dim3(256), 0, stream, W_node, Wt, counters);
  hipLaunchKernelGGL(bucket_kernel, dim3((B_ * NINT + 255) / 256), dim3(256), 0, stream,
                     node_type, counters, buckets);
  hipLaunchKernelGGL(dest_kernel, dim3((187488 + 255) / 256), dim3(256), 0, stream,
                     buckets, counters, wdest_all, rsrc6);
  hipLaunchKernelGGL(leaf_kernel, dim3(1024), dim3(256), 0, stream,
                     leaf_box, leaf_sem, W_box, b_box, W_sem, b_sem, rsrc6, G[5]);

  const int lvl_base[6] = {0, 48, 288, 1488, 7488, 37488};
  const int off_tab[6]  = {0, 1, 6, 31, 156, 781};
  const int woff[6]     = {0, 0, 80, 480, 2480, 12480};  // wdest region of child level l
  for (int l = 5; l >= 0; --l) {
    int cap = B_ * n_tab[l];
    int tiles = (cap + 127) / 128;
    const int* wdp = (l >= 1) ? (wdest_all + woff[l]) : nullptr;
    hipLaunchKernelGGL(level_kernel, dim3(tiles, 3, 2), dim3(256), 0, stream,
                       G[l], (l >= 1) ? G[l - 1] : f0, buckets + lvl_base[l],
                       counters + l * 3, Wt, b_node, internal_box, W_box, b_box,
                       wdp, n_tab[l], off_tab[l], cap);
  }
  hipLaunchKernelGGL(head_kernel, dim3(16), dim3(256), 0, stream,
                     f0, eps, W1, b1, Wmu, bmu, Wvar, bvar, out);
}